// Round 7
// baseline (1922.446 us; speedup 1.0000x reference)
//
#include <hip/hip_runtime.h>
#include <hip/hip_bf16.h>
#include <hip/hip_fp16.h>
#include <math.h>

#define B_ 4
#define N_ 2048
#define D_ 512

typedef __bf16    bf16x8  __attribute__((ext_vector_type(8)));
typedef float     floatx4 __attribute__((ext_vector_type(4)));
typedef _Float16  half8   __attribute__((ext_vector_type(8)));

#if __has_builtin(__builtin_amdgcn_exp2f)
__device__ __forceinline__ float fexp2(float x) { return __builtin_amdgcn_exp2f(x); }
#else
__device__ __forceinline__ float fexp2(float x) { return exp2f(x); }
#endif
#if __has_builtin(__builtin_amdgcn_logf)
__device__ __forceinline__ float flog2(float x) { return __builtin_amdgcn_logf(x); }
#else
__device__ __forceinline__ float flog2(float x) { return __log2f(x); }
#endif

// ---------------------------------------------------------------------------
__device__ __forceinline__ void gload16(const void* g, void* l) {
  __builtin_amdgcn_global_load_lds(
      (const __attribute__((address_space(1))) void*)g,
      (__attribute__((address_space(3))) void*)l, 16, 0, 0);
}

// ---------------------------------------------------------------------------
// L2-normalize rows of (rows, 512) f32 -> bf16
// ---------------------------------------------------------------------------
__global__ __launch_bounds__(256) void norm_kernel(const float* __restrict__ in,
                                                   __hip_bfloat16* __restrict__ out) {
  const size_t row = blockIdx.x;
  const int t = threadIdx.x;
  const float* src = in + row * D_;
  float v0 = src[t], v1 = src[t + 256];
  float ss = fmaf(v0, v0, v1 * v1);
#pragma unroll
  for (int off = 1; off < 64; off <<= 1) ss += __shfl_xor(ss, off);
  __shared__ float red[4];
  if ((t & 63) == 0) red[t >> 6] = ss;
  __syncthreads();
  const float tot = red[0] + red[1] + red[2] + red[3];
  const float scale = 1.0f / fmaxf(sqrtf(tot), 1e-12f);
  out[row * D_ + t]       = __float2bfloat16(v0 * scale);
  out[row * D_ + t + 256] = __float2bfloat16(v1 * scale);
}

// ---------------------------------------------------------------------------
// Batched NT GEMM producing the 3 Gram matrices in one dispatch.
// ---------------------------------------------------------------------------
__global__ __launch_bounds__(256) void gram_gemm(const __hip_bfloat16* __restrict__ X,
                                                 const __hip_bfloat16* __restrict__ Y,
                                                 __half* __restrict__ Gxy,
                                                 __half* __restrict__ Gxx,
                                                 __half* __restrict__ Gyy) {
  __shared__ __hip_bfloat16 As[128 * 32];
  __shared__ __hip_bfloat16 Bs[128 * 32];
  const int t = threadIdx.x;
  const int wave = t >> 6, lane = t & 63;
  const int bm0 = blockIdx.x * 128, bn0 = blockIdx.y * 128;
  const int mat = blockIdx.z >> 2;
  const size_t bb = blockIdx.z & 3;
  const __hip_bfloat16* Ab = (mat == 2 ? Y : X) + bb * (size_t)(N_ * D_);
  const __hip_bfloat16* Bb = (mat == 1 ? X : Y) + bb * (size_t)(N_ * D_);
  __half* Gb = (mat == 0 ? Gxy : mat == 1 ? Gxx : Gyy) + bb * (size_t)N_ * N_;

  floatx4 acc[4][4] = {};
  const int wr = wave >> 1, wc = wave & 1;
  const int srow = t >> 2;
  const int scol = (t & 3) * 8;
  char* AsB = (char*)As;
  char* BsB = (char*)Bs;
  const int ldsOff = wave * 1024;

  for (int k0 = 0; k0 < D_; k0 += 32) {
    __syncthreads();
    gload16(Ab + (size_t)(bm0 + srow)      * D_ + k0 + scol, AsB + ldsOff);
    gload16(Ab + (size_t)(bm0 + 64 + srow) * D_ + k0 + scol, AsB + 4096 + ldsOff);
    gload16(Bb + (size_t)(bn0 + srow)      * D_ + k0 + scol, BsB + ldsOff);
    gload16(Bb + (size_t)(bn0 + 64 + srow) * D_ + k0 + scol, BsB + 4096 + ldsOff);
    __syncthreads();

    const int lrow = lane & 15, lk = (lane >> 4) * 8;
    bf16x8 af[4], bfr[4];
#pragma unroll
    for (int mi = 0; mi < 4; ++mi)
      af[mi] = *(const bf16x8*)((const char*)As + ((wr * 64 + mi * 16 + lrow) * 32 + lk) * 2);
#pragma unroll
    for (int ni = 0; ni < 4; ++ni)
      bfr[ni] = *(const bf16x8*)((const char*)Bs + ((wc * 64 + ni * 16 + lrow) * 32 + lk) * 2);
#pragma unroll
    for (int mi = 0; mi < 4; ++mi)
#pragma unroll
      for (int ni = 0; ni < 4; ++ni)
        acc[mi][ni] = __builtin_amdgcn_mfma_f32_16x16x32_bf16(af[mi], bfr[ni], acc[mi][ni], 0, 0, 0);
  }

  const int orow = (lane >> 4) * 4, ocol = lane & 15;
#pragma unroll
  for (int mi = 0; mi < 4; ++mi)
#pragma unroll
    for (int ni = 0; ni < 4; ++ni) {
      const int row = bm0 + wr * 64 + mi * 16 + orow;
      const int col = bn0 + wc * 64 + ni * 16 + ocol;
#pragma unroll
      for (int r = 0; r < 4; ++r)
        Gb[(size_t)(row + r) * N_ + col] = __float2half(acc[mi][ni][r]);
    }
}

// ---------------------------------------------------------------------------
// Fused streaming pass, stall-free inner loop. 1536 blocks, mat = bid % 3:
//   mat 0 (Gxy): row-LSE -> f_ba (slot 0); column-LSE partials -> colPart
//   mat 1 (Gxx): row-LSE -> f_aa (slot 2)
//   mat 2 (Gyy): row-LSE -> g_bb (slot 3)
// Block = (mat, b, 16-row stripe). Wave owns a 512-col slice; lane owns 8 cols.
// R6 lesson: per-iteration cross-lane butterflies + potR loads serialize the
// load pipeline (3.8 TB/s). Here the hot loop is pure load->VALU: per-lane
// online (m,s) for each of 16 rows (rm/rs in regs), butterflies batched at
// stripe end (16 independent chains), potR hoisted to one pre-loop load.
// colPart stores single-float LSE partials (merge treats L as (m=L,s=1)).
// MODE 0: init write. MODE 1: damped 0.5(old+new). MODE 2: loss accumulate.
// ---------------------------------------------------------------------------
#define L2E_ 1.44269504088896f
#define LN2_ 0.69314718055995f

template <int MODE>
__global__ __launch_bounds__(256) void sink_stream(
    const __half* __restrict__ Gxy, const __half* __restrict__ Gxx,
    const __half* __restrict__ Gyy,
    const float* __restrict__ potOld, float* __restrict__ potNew,
    float* __restrict__ colPart, float eps, float* __restrict__ out) {
  __shared__ float2 part[4][16];

  const int bid = blockIdx.x;
  const int mat = bid % 3;
  const int rem = bid / 3;                 // 0..511
  const int b = rem >> 7, stripe = rem & 127;
  const int lane = threadIdx.x & 63, wave = threadIdx.x >> 6;
  const int c0 = wave * 512 + lane * 8;

  const float inv_eps = 1.0f / eps;
  const float ieL  = inv_eps * L2E_;
  const float hbL  = (-7.62461898616f - inv_eps) * L2E_;  // (-log 2048 - 1/eps)*log2e
  const float negEpsLn2 = -eps * LN2_;

  const __half* G = (mat == 0 ? Gxy : mat == 1 ? Gxx : Gyy) + (size_t)b * N_ * N_;
  const int hIdx = (mat == 0) ? 1 : (mat == 1) ? 2 : 3;
  const int oIdx = (mat == 0) ? 0 : hIdx;
  const float* potH = potOld + ((size_t)hIdx * B_ + b) * N_;
  const float* potR = potOld + ((size_t)0    * B_ + b) * N_;
  const float* potO = potOld + ((size_t)oIdx * B_ + b) * N_;
  float*       potW = potNew + ((size_t)oIdx * B_ + b) * N_;

  const int rbase = stripe * 16;

  // h for the 8 owned columns (log2 domain)
  float hh[8];
  if constexpr (MODE == 0) {
#pragma unroll
    for (int e = 0; e < 8; ++e) hh[e] = hbL;
  } else {
    const float4 a = *(const float4*)(potH + c0);
    const float4 c = *(const float4*)(potH + c0 + 4);
    hh[0] = fmaf(a.x, ieL, hbL); hh[1] = fmaf(a.y, ieL, hbL);
    hh[2] = fmaf(a.z, ieL, hbL); hh[3] = fmaf(a.w, ieL, hbL);
    hh[4] = fmaf(c.x, ieL, hbL); hh[5] = fmaf(c.y, ieL, hbL);
    hh[6] = fmaf(c.z, ieL, hbL); hh[7] = fmaf(c.w, ieL, hbL);
  }

  // hoisted row potentials: lane (r&15) holds row rbase+r's transformed value
  float hrP = hbL;
  if (mat == 0 && MODE != 0)
    hrP = fmaf(potR[rbase + (lane & 15)], ieL, hbL);

  // online column accumulators (mat 0 only)
  float colm[8], colsum[8];
#pragma unroll
  for (int e = 0; e < 8; ++e) { colm[e] = -3.0e38f; colsum[e] = 0.0f; }

  // per-lane online row state for the 16 stripe rows
  float rm[16], rs[16];
#pragma unroll
  for (int r = 0; r < 16; ++r) { rm[r] = -3.0e38f; rs[r] = 0.0f; }

  const __half* gbase = G + (size_t)rbase * N_ + c0;

  half8 cur[4], nxt[4];
#pragma unroll
  for (int r = 0; r < 4; ++r) cur[r] = *(const half8*)(gbase + (size_t)r * N_);

#pragma unroll
  for (int it = 0; it < 4; ++it) {
    if (it < 3) {
#pragma unroll
      for (int r = 0; r < 4; ++r)
        nxt[r] = *(const half8*)(gbase + (size_t)((it + 1) * 4 + r) * N_);
    }

#pragma unroll
    for (int r = 0; r < 4; ++r) {
      const int row = it * 4 + r;
      float u[8], t[8];
#pragma unroll
      for (int e = 0; e < 8; ++e) u[e] = (float)cur[r][e] * ieL;
#pragma unroll
      for (int e = 0; e < 8; ++e) t[e] = u[e] + hh[e];
      const float lm = fmaxf(fmaxf(fmaxf(t[0], t[1]), fmaxf(t[2], t[3])),
                             fmaxf(fmaxf(t[4], t[5]), fmaxf(t[6], t[7])));
      const float nm = fmaxf(rm[row], lm);
      float es = 0.0f;
#pragma unroll
      for (int e = 0; e < 8; ++e) es += fexp2(t[e] - nm);
      rs[row] = fmaf(rs[row], fexp2(rm[row] - nm), es);
      rm[row] = nm;

      if (mat == 0) {
        const float hr = __shfl(hrP, row);
#pragma unroll
        for (int e = 0; e < 8; ++e) {
          const float sv = u[e] + hr;
          const float cm = fmaxf(colm[e], sv);
          colsum[e] = fmaf(colsum[e], fexp2(colm[e] - cm), fexp2(sv - cm));
          colm[e] = cm;
        }
      }
    }

    if (it < 3) {
#pragma unroll
      for (int r = 0; r < 4; ++r) cur[r] = nxt[r];
    }
  }

  // column partial writeout: single-float LSE partials, coalesced float4 x2
  if (mat == 0) {
    float4 o0, o1;
    o0.x = colm[0] + flog2(colsum[0]); o0.y = colm[1] + flog2(colsum[1]);
    o0.z = colm[2] + flog2(colsum[2]); o0.w = colm[3] + flog2(colsum[3]);
    o1.x = colm[4] + flog2(colsum[4]); o1.y = colm[5] + flog2(colsum[5]);
    o1.z = colm[6] + flog2(colsum[6]); o1.w = colm[7] + flog2(colsum[7]);
    float* cp = colPart + ((size_t)(b * 128 + stripe) * 2048 + c0);
    *(float4*)cp = o0;
    *(float4*)(cp + 4) = o1;
  }

  // batched row butterflies: 16 independent (m,s) merge chains
#pragma unroll
  for (int r = 0; r < 16; ++r) {
    float m = rm[r], s = rs[r];
#pragma unroll
    for (int off = 1; off < 64; off <<= 1) {
      const float om = __shfl_xor(m, off);
      const float os = __shfl_xor(s, off);
      const float n2 = fmaxf(m, om);
      s = fmaf(s, fexp2(m - n2), os * fexp2(om - n2));
      m = n2;
    }
    if (lane == 0) part[wave][r] = make_float2(m, s);
  }
  __syncthreads();

  // wave 0 merges the 4 slice-partials per row and writes the row potential
  float vfin = 0.0f;
  if (wave == 0 && lane < 16) {
    float2 q = part[0][lane];
    float m = q.x, s = q.y;
#pragma unroll
    for (int w = 1; w < 4; ++w) {
      const float2 q2 = part[w][lane];
      const float n2 = fmaxf(m, q2.x);
      s = fmaf(s, fexp2(m - n2), q2.y * fexp2(q2.x - n2));
      m = n2;
    }
    const float v = negEpsLn2 * (m + flog2(s));
    const int r = rbase + lane;
    if constexpr (MODE == 0) {
      potW[r] = v;
    } else if constexpr (MODE == 1) {
      potW[r] = 0.5f * (potO[r] + v);
    } else {
      vfin = v;
    }
  }

  if constexpr (MODE == 2) {
#pragma unroll
    for (int off = 1; off < 64; off <<= 1) vfin += __shfl_xor(vfin, off);
    if (threadIdx.x == 0) {
      const float sign = (mat == 0) ? 1.0f : -1.0f;
      atomicAdd(out, sign * vfin * (1.0f / (2048.0f * B_)));
    }
  }
}

// ---------------------------------------------------------------------------
// Merge single-float column partials across 128 stripes -> g_ab (slot 1).
// 128 blocks x 256. Block = 64 global columns; wave w merges stripes
// [w*32, w*32+32) treating each L as (m=L, s=1); LDS merge; wave 0 finalizes.
// ---------------------------------------------------------------------------
template <int MODE>
__global__ __launch_bounds__(256) void sink_merge(
    const float* __restrict__ colPart, const float* __restrict__ potOld,
    float* __restrict__ potNew, float eps, float* __restrict__ out) {
  __shared__ float2 mp[3][64];
  const int lane = threadIdx.x & 63, sub = threadIdx.x >> 6;
  const int colg = blockIdx.x * 64 + lane;          // 0..8191
  const int b = colg >> 11, col = colg & 2047;
  const float negEpsLn2 = -eps * LN2_;

  float m = -3.0e38f, s = 0.0f;
  const float* cp = colPart + ((size_t)(b * 128 + sub * 32)) * 2048 + col;
#pragma unroll
  for (int st = 0; st < 32; ++st) {
    const float L = cp[(size_t)st * 2048];
    const float nm = fmaxf(m, L);
    s = fmaf(s, fexp2(m - nm), fexp2(L - nm));
    m = nm;
  }
  if (sub != 0) mp[sub - 1][lane] = make_float2(m, s);
  __syncthreads();

  float vfin = 0.0f;
  if (sub == 0) {
#pragma unroll
    for (int w = 0; w < 3; ++w) {
      const float2 q = mp[w][lane];
      const float nm = fmaxf(m, q.x);
      s = fmaf(s, fexp2(m - nm), q.y * fexp2(q.x - nm));
      m = nm;
    }
    const float v = negEpsLn2 * (m + flog2(s));
    if constexpr (MODE == 0) {
      potNew[((size_t)1 * B_ + b) * N_ + col] = v;
    } else if constexpr (MODE == 1) {
      potNew[((size_t)1 * B_ + b) * N_ + col] =
          0.5f * (potOld[((size_t)1 * B_ + b) * N_ + col] + v);
    } else {
      vfin = v;
    }
  }

  if constexpr (MODE == 2) {
#pragma unroll
    for (int off = 1; off < 64; off <<= 1) vfin += __shfl_xor(vfin, off);
    __shared__ float red[4];
    if ((threadIdx.x & 63) == 0) red[sub] = vfin;
    __syncthreads();
    if (threadIdx.x == 0)
      atomicAdd(out, (red[0] + red[1] + red[2] + red[3]) * (1.0f / (2048.0f * B_)));
  }
}

// ---------------------------------------------------------------------------
extern "C" void kernel_launch(void* const* d_in, const int* in_sizes, int n_in,
                              void* d_out, int out_size, void* d_ws, size_t ws_size,
                              hipStream_t stream) {
  const float* E_p = (const float*)d_in[0];
  const float* E_t = (const float*)d_in[1];
  float* out = (float*)d_out;
  char* ws = (char*)d_ws;

  size_t off = 0;
  auto alloc = [&](size_t bytes) {
    void* p = ws + off;
    off += (bytes + 255) & ~(size_t)255;
    return p;
  };
  __hip_bfloat16* Xb = (__hip_bfloat16*)alloc((size_t)B_ * N_ * D_ * 2);
  __hip_bfloat16* Yb = (__hip_bfloat16*)alloc((size_t)B_ * N_ * D_ * 2);
  __half* Gxy = (__half*)alloc((size_t)B_ * N_ * N_ * 2);
  __half* Gxx = (__half*)alloc((size_t)B_ * N_ * N_ * 2);
  __half* Gyy = (__half*)alloc((size_t)B_ * N_ * N_ * 2);
  float* potA = (float*)alloc((size_t)4 * B_ * N_ * 4);
  float* potB = (float*)alloc((size_t)4 * B_ * N_ * 4);
  float* colPart = (float*)alloc((size_t)B_ * 128 * 2048 * 4);

  norm_kernel<<<B_ * N_, 256, 0, stream>>>(E_p, Xb);
  norm_kernel<<<B_ * N_, 256, 0, stream>>>(E_t, Yb);

  dim3 gg(16, 16, 12);
  gram_gemm<<<gg, 256, 0, stream>>>(Xb, Yb, Gxy, Gxx, Gyy);

  // epsilon schedule (numpy arange semantics, double precision)
  float epsl[48];
  int ne = 0;
  epsl[ne++] = 4.0f;
  {
    const double lstart = 2.0 * log(2.0);
    const double lstop  = 2.0 * log(0.05);
    const double lstep  = 2.0 * log(0.9);
    for (int k = 0;; ++k) {
      const double v = lstart + k * lstep;
      if (!(v > lstop)) break;
      epsl[ne++] = (float)exp(v);
    }
  }
  epsl[ne++] = 0.0025f;

  (void)hipMemsetAsync(d_out, 0, sizeof(float), stream);

  // init at eps0
  sink_stream<0><<<1536, 256, 0, stream>>>(Gxy, Gxx, Gyy, potA, potA, colPart,
                                           epsl[0], nullptr);
  sink_merge<0><<<128, 256, 0, stream>>>(colPart, potA, potA, epsl[0], nullptr);

  // damped scan over the schedule
  float* cur = potA;
  float* nxt = potB;
  for (int i = 0; i < ne; ++i) {
    sink_stream<1><<<1536, 256, 0, stream>>>(Gxy, Gxx, Gyy, cur, nxt, colPart,
                                             epsl[i], nullptr);
    sink_merge<1><<<128, 256, 0, stream>>>(colPart, cur, nxt, epsl[i], nullptr);
    float* tmp = cur; cur = nxt; nxt = tmp;
  }

  // final extrapolation + loss
  sink_stream<2><<<1536, 256, 0, stream>>>(Gxy, Gxx, Gyy, cur, cur, colPart,
                                           epsl[ne - 1], out);
  sink_merge<2><<<128, 256, 0, stream>>>(colPart, cur, cur, epsl[ne - 1], out);
}

// Round 8
// 1318.006 us; speedup vs baseline: 1.4586x; 1.4586x over previous
//
#include <hip/hip_runtime.h>
#include <hip/hip_bf16.h>
#include <hip/hip_fp16.h>
#include <math.h>

#define B_ 4
#define N_ 2048
#define D_ 512

typedef __bf16    bf16x8  __attribute__((ext_vector_type(8)));
typedef float     floatx4 __attribute__((ext_vector_type(4)));
typedef _Float16  half8   __attribute__((ext_vector_type(8)));

#if __has_builtin(__builtin_amdgcn_exp2f)
__device__ __forceinline__ float fexp2(float x) { return __builtin_amdgcn_exp2f(x); }
#else
__device__ __forceinline__ float fexp2(float x) { return exp2f(x); }
#endif
#if __has_builtin(__builtin_amdgcn_logf)
__device__ __forceinline__ float flog2(float x) { return __builtin_amdgcn_logf(x); }
#else
__device__ __forceinline__ float flog2(float x) { return __log2f(x); }
#endif

// ---------------------------------------------------------------------------
__device__ __forceinline__ void gload16(const void* g, void* l) {
  __builtin_amdgcn_global_load_lds(
      (const __attribute__((address_space(1))) void*)g,
      (__attribute__((address_space(3))) void*)l, 16, 0, 0);
}

// ---------------------------------------------------------------------------
// L2-normalize rows of (rows, 512) f32 -> bf16
// ---------------------------------------------------------------------------
__global__ __launch_bounds__(256) void norm_kernel(const float* __restrict__ in,
                                                   __hip_bfloat16* __restrict__ out) {
  const size_t row = blockIdx.x;
  const int t = threadIdx.x;
  const float* src = in + row * D_;
  float v0 = src[t], v1 = src[t + 256];
  float ss = fmaf(v0, v0, v1 * v1);
#pragma unroll
  for (int off = 1; off < 64; off <<= 1) ss += __shfl_xor(ss, off);
  __shared__ float red[4];
  if ((t & 63) == 0) red[t >> 6] = ss;
  __syncthreads();
  const float tot = red[0] + red[1] + red[2] + red[3];
  const float scale = 1.0f / fmaxf(sqrtf(tot), 1e-12f);
  out[row * D_ + t]       = __float2bfloat16(v0 * scale);
  out[row * D_ + t + 256] = __float2bfloat16(v1 * scale);
}

// ---------------------------------------------------------------------------
// Batched NT GEMM producing the 3 Gram matrices in one dispatch.
// ---------------------------------------------------------------------------
__global__ __launch_bounds__(256) void gram_gemm(const __hip_bfloat16* __restrict__ X,
                                                 const __hip_bfloat16* __restrict__ Y,
                                                 __half* __restrict__ Gxy,
                                                 __half* __restrict__ Gxx,
                                                 __half* __restrict__ Gyy) {
  __shared__ __hip_bfloat16 As[128 * 32];
  __shared__ __hip_bfloat16 Bs[128 * 32];
  const int t = threadIdx.x;
  const int wave = t >> 6, lane = t & 63;
  const int bm0 = blockIdx.x * 128, bn0 = blockIdx.y * 128;
  const int mat = blockIdx.z >> 2;
  const size_t bb = blockIdx.z & 3;
  const __hip_bfloat16* Ab = (mat == 2 ? Y : X) + bb * (size_t)(N_ * D_);
  const __hip_bfloat16* Bb = (mat == 1 ? X : Y) + bb * (size_t)(N_ * D_);
  __half* Gb = (mat == 0 ? Gxy : mat == 1 ? Gxx : Gyy) + bb * (size_t)N_ * N_;

  floatx4 acc[4][4] = {};
  const int wr = wave >> 1, wc = wave & 1;
  const int srow = t >> 2;
  const int scol = (t & 3) * 8;
  char* AsB = (char*)As;
  char* BsB = (char*)Bs;
  const int ldsOff = wave * 1024;

  for (int k0 = 0; k0 < D_; k0 += 32) {
    __syncthreads();
    gload16(Ab + (size_t)(bm0 + srow)      * D_ + k0 + scol, AsB + ldsOff);
    gload16(Ab + (size_t)(bm0 + 64 + srow) * D_ + k0 + scol, AsB + 4096 + ldsOff);
    gload16(Bb + (size_t)(bn0 + srow)      * D_ + k0 + scol, BsB + ldsOff);
    gload16(Bb + (size_t)(bn0 + 64 + srow) * D_ + k0 + scol, BsB + 4096 + ldsOff);
    __syncthreads();

    const int lrow = lane & 15, lk = (lane >> 4) * 8;
    bf16x8 af[4], bfr[4];
#pragma unroll
    for (int mi = 0; mi < 4; ++mi)
      af[mi] = *(const bf16x8*)((const char*)As + ((wr * 64 + mi * 16 + lrow) * 32 + lk) * 2);
#pragma unroll
    for (int ni = 0; ni < 4; ++ni)
      bfr[ni] = *(const bf16x8*)((const char*)Bs + ((wc * 64 + ni * 16 + lrow) * 32 + lk) * 2);
#pragma unroll
    for (int mi = 0; mi < 4; ++mi)
#pragma unroll
      for (int ni = 0; ni < 4; ++ni)
        acc[mi][ni] = __builtin_amdgcn_mfma_f32_16x16x32_bf16(af[mi], bfr[ni], acc[mi][ni], 0, 0, 0);
  }

  const int orow = (lane >> 4) * 4, ocol = lane & 15;
#pragma unroll
  for (int mi = 0; mi < 4; ++mi)
#pragma unroll
    for (int ni = 0; ni < 4; ++ni) {
      const int row = bm0 + wr * 64 + mi * 16 + orow;
      const int col = bn0 + wc * 64 + ni * 16 + ocol;
#pragma unroll
      for (int r = 0; r < 4; ++r)
        Gb[(size_t)(row + r) * N_ + col] = __float2half(acc[mi][ni][r]);
    }
}

// ---------------------------------------------------------------------------
// Fused streaming pass, predicted-shift softmax (no max chains, 1 exp2/elem).
// 1536 blocks, mat = bid % 3:
//   mat 0 (Gxy): row-LSE -> f_ba (slot 0); column partials -> colPart
//   mat 1 (Gxx): row-LSE -> f_aa (slot 2)
//   mat 2 (Gyy): row-LSE -> g_bb (slot 3)
// Key identity: with shifts taken from the previous iteration's potentials,
// w = 2^{ ieL*G + hh[c] + (hr - hbL) } is the transport-plan entry and serves
// BOTH the row accumulation (rsum[r] += w) and the column accumulation
// (colsum[c] += w). Inner loop: cvt + fma + exp2 + 2 add per element, zero
// cross-lane ops, zero fmax. Row finalize: v = -eps*ln2*(log2(S)+hbL-hr).
// Col partial: L = log2(colsum) - (hh - hbL). Overflow-safe: w ~ plan entries
// (bounded ~n), potential drift per iteration << fp32's 2^±126 range.
// MODE 0: init write. MODE 1: damped 0.5(old+new). MODE 2: loss accumulate.
// ---------------------------------------------------------------------------
#define L2E_ 1.44269504088896f
#define LN2_ 0.69314718055995f

template <int MODE>
__global__ __launch_bounds__(256) void sink_stream(
    const __half* __restrict__ Gxy, const __half* __restrict__ Gxx,
    const __half* __restrict__ Gyy,
    const float* __restrict__ potOld, float* __restrict__ potNew,
    float* __restrict__ colPart, float eps, float* __restrict__ out) {
  __shared__ float part[4][16];

  const int bid = blockIdx.x;
  const int mat = bid % 3;
  const int rem = bid / 3;                 // 0..511
  const int b = rem >> 7, stripe = rem & 127;
  const int lane = threadIdx.x & 63, wave = threadIdx.x >> 6;
  const int c0 = wave * 512 + lane * 8;

  const float inv_eps = 1.0f / eps;
  const float ieL  = inv_eps * L2E_;
  const float hbL  = (-7.62461898616f - inv_eps) * L2E_;  // (-log 2048 - 1/eps)*log2e
  const float negEpsLn2 = -eps * LN2_;

  const __half* G = (mat == 0 ? Gxy : mat == 1 ? Gxx : Gyy) + (size_t)b * N_ * N_;
  const int hIdx = (mat == 0) ? 1 : (mat == 1) ? 2 : 3;
  const int oIdx = (mat == 0) ? 0 : hIdx;
  const float* potH = potOld + ((size_t)hIdx * B_ + b) * N_;
  const float* potO = potOld + ((size_t)oIdx * B_ + b) * N_;
  float*       potW = potNew + ((size_t)oIdx * B_ + b) * N_;

  const int rbase = stripe * 16;

  // h for the 8 owned columns (log2 domain)
  float hh[8];
  if constexpr (MODE == 0) {
#pragma unroll
    for (int e = 0; e < 8; ++e) hh[e] = hbL;
  } else {
    const float4 a = *(const float4*)(potH + c0);
    const float4 c = *(const float4*)(potH + c0 + 4);
    hh[0] = fmaf(a.x, ieL, hbL); hh[1] = fmaf(a.y, ieL, hbL);
    hh[2] = fmaf(a.z, ieL, hbL); hh[3] = fmaf(a.w, ieL, hbL);
    hh[4] = fmaf(c.x, ieL, hbL); hh[5] = fmaf(c.y, ieL, hbL);
    hh[6] = fmaf(c.z, ieL, hbL); hh[7] = fmaf(c.w, ieL, hbL);
  }

  // hoisted row-side potentials: lane r<16 holds row rbase+r's transformed value
  float hrP = hbL;
  if constexpr (MODE != 0) hrP = fmaf(potO[rbase + (lane & 15)], ieL, hbL);

  float rsum[16];
#pragma unroll
  for (int r = 0; r < 16; ++r) rsum[r] = 0.0f;
  float colsum[8];
#pragma unroll
  for (int e = 0; e < 8; ++e) colsum[e] = 0.0f;

  const __half* gbase = G + (size_t)rbase * N_ + c0;

  half8 cur[4], nxt[4];
#pragma unroll
  for (int r = 0; r < 4; ++r) cur[r] = *(const half8*)(gbase + (size_t)r * N_);

#pragma unroll
  for (int it = 0; it < 4; ++it) {
    if (it < 3) {
#pragma unroll
      for (int r = 0; r < 4; ++r)
        nxt[r] = *(const half8*)(gbase + (size_t)((it + 1) * 4 + r) * N_);
    }

#pragma unroll
    for (int r = 0; r < 4; ++r) {
      const int row = it * 4 + r;
      const float hb = __shfl(hrP, row) - hbL;   // hr - hbL (0 in MODE 0)
      float w[8];
#pragma unroll
      for (int e = 0; e < 8; ++e)
        w[e] = fexp2(fmaf((float)cur[r][e], ieL, hh[e] + hb));
      if (mat == 0) {
#pragma unroll
        for (int e = 0; e < 8; ++e) colsum[e] += w[e];
      }
      rsum[row] = ((w[0] + w[1]) + (w[2] + w[3])) + ((w[4] + w[5]) + (w[6] + w[7]));
    }

    if (it < 3) {
#pragma unroll
      for (int r = 0; r < 4; ++r) cur[r] = nxt[r];
    }
  }

  // column partial writeout: L = log2(colsum) - (hh - hbL), coalesced float4 x2
  if (mat == 0) {
    float4 o0, o1;
    o0.x = flog2(colsum[0]) - (hh[0] - hbL);
    o0.y = flog2(colsum[1]) - (hh[1] - hbL);
    o0.z = flog2(colsum[2]) - (hh[2] - hbL);
    o0.w = flog2(colsum[3]) - (hh[3] - hbL);
    o1.x = flog2(colsum[4]) - (hh[4] - hbL);
    o1.y = flog2(colsum[5]) - (hh[5] - hbL);
    o1.z = flog2(colsum[6]) - (hh[6] - hbL);
    o1.w = flog2(colsum[7]) - (hh[7] - hbL);
    float* cp = colPart + ((size_t)(b * 128 + stripe) * 2048 + c0);
    *(float4*)cp = o0;
    *(float4*)(cp + 4) = o1;
  }

  // batched add-only butterflies: 16 independent sum chains
#pragma unroll
  for (int r = 0; r < 16; ++r) {
    float s = rsum[r];
#pragma unroll
    for (int off = 1; off < 64; off <<= 1) s += __shfl_xor(s, off);
    if (lane == 0) part[wave][r] = s;
  }
  __syncthreads();

  // wave 0 merges 4 slice sums per row and writes the row potential
  float vfin = 0.0f;
  if (wave == 0 && lane < 16) {
    const float S = part[0][lane] + part[1][lane] + part[2][lane] + part[3][lane];
    const float v = negEpsLn2 * (flog2(S) + hbL - hrP);  // hrP = this row's value
    const int r = rbase + lane;
    if constexpr (MODE == 0) {
      potW[r] = v;
    } else if constexpr (MODE == 1) {
      const float vOld = -negEpsLn2 * (hrP - hbL);       // recover old potential
      potW[r] = 0.5f * (vOld + v);
    } else {
      vfin = v;
    }
  }

  if constexpr (MODE == 2) {
#pragma unroll
    for (int off = 1; off < 64; off <<= 1) vfin += __shfl_xor(vfin, off);
    if (threadIdx.x == 0) {
      const float sign = (mat == 0) ? 1.0f : -1.0f;
      atomicAdd(out, sign * vfin * (1.0f / (2048.0f * B_)));
    }
  }
}

// ---------------------------------------------------------------------------
// Merge single-float column-LSE partials across 128 stripes -> g_ab (slot 1).
// 128 blocks x 256. Block = 64 global columns; wave w merges stripes
// [w*32, w*32+32) treating each L as (m=L, s=1); LDS merge; wave 0 finalizes.
// Online-max here (cheap, 3.4 MB total) keeps the merge unconditionally safe.
// ---------------------------------------------------------------------------
template <int MODE>
__global__ __launch_bounds__(256) void sink_merge(
    const float* __restrict__ colPart, const float* __restrict__ potOld,
    float* __restrict__ potNew, float eps, float* __restrict__ out) {
  __shared__ float2 mp[3][64];
  const int lane = threadIdx.x & 63, sub = threadIdx.x >> 6;
  const int colg = blockIdx.x * 64 + lane;          // 0..8191
  const int b = colg >> 11, col = colg & 2047;
  const float negEpsLn2 = -eps * LN2_;

  float m = -3.0e38f, s = 0.0f;
  const float* cp = colPart + ((size_t)(b * 128 + sub * 32)) * 2048 + col;
#pragma unroll
  for (int st = 0; st < 32; ++st) {
    const float L = cp[(size_t)st * 2048];
    const float nm = fmaxf(m, L);
    s = fmaf(s, fexp2(m - nm), fexp2(L - nm));
    m = nm;
  }
  if (sub != 0) mp[sub - 1][lane] = make_float2(m, s);
  __syncthreads();

  float vfin = 0.0f;
  if (sub == 0) {
#pragma unroll
    for (int w = 0; w < 3; ++w) {
      const float2 q = mp[w][lane];
      const float nm = fmaxf(m, q.x);
      s = fmaf(s, fexp2(m - nm), q.y * fexp2(q.x - nm));
      m = nm;
    }
    const float v = negEpsLn2 * (m + flog2(s));
    if constexpr (MODE == 0) {
      potNew[((size_t)1 * B_ + b) * N_ + col] = v;
    } else if constexpr (MODE == 1) {
      potNew[((size_t)1 * B_ + b) * N_ + col] =
          0.5f * (potOld[((size_t)1 * B_ + b) * N_ + col] + v);
    } else {
      vfin = v;
    }
  }

  if constexpr (MODE == 2) {
#pragma unroll
    for (int off = 1; off < 64; off <<= 1) vfin += __shfl_xor(vfin, off);
    __shared__ float red[4];
    if ((threadIdx.x & 63) == 0) red[sub] = vfin;
    __syncthreads();
    if (threadIdx.x == 0)
      atomicAdd(out, (red[0] + red[1] + red[2] + red[3]) * (1.0f / (2048.0f * B_)));
  }
}

// ---------------------------------------------------------------------------
extern "C" void kernel_launch(void* const* d_in, const int* in_sizes, int n_in,
                              void* d_out, int out_size, void* d_ws, size_t ws_size,
                              hipStream_t stream) {
  const float* E_p = (const float*)d_in[0];
  const float* E_t = (const float*)d_in[1];
  float* out = (float*)d_out;
  char* ws = (char*)d_ws;

  size_t off = 0;
  auto alloc = [&](size_t bytes) {
    void* p = ws + off;
    off += (bytes + 255) & ~(size_t)255;
    return p;
  };
  __hip_bfloat16* Xb = (__hip_bfloat16*)alloc((size_t)B_ * N_ * D_ * 2);
  __hip_bfloat16* Yb = (__hip_bfloat16*)alloc((size_t)B_ * N_ * D_ * 2);
  __half* Gxy = (__half*)alloc((size_t)B_ * N_ * N_ * 2);
  __half* Gxx = (__half*)alloc((size_t)B_ * N_ * N_ * 2);
  __half* Gyy = (__half*)alloc((size_t)B_ * N_ * N_ * 2);
  float* potA = (float*)alloc((size_t)4 * B_ * N_ * 4);
  float* potB = (float*)alloc((size_t)4 * B_ * N_ * 4);
  float* colPart = (float*)alloc((size_t)B_ * 128 * 2048 * 4);

  norm_kernel<<<B_ * N_, 256, 0, stream>>>(E_p, Xb);
  norm_kernel<<<B_ * N_, 256, 0, stream>>>(E_t, Yb);

  dim3 gg(16, 16, 12);
  gram_gemm<<<gg, 256, 0, stream>>>(Xb, Yb, Gxy, Gxx, Gyy);

  // epsilon schedule (numpy arange semantics, double precision)
  float epsl[48];
  int ne = 0;
  epsl[ne++] = 4.0f;
  {
    const double lstart = 2.0 * log(2.0);
    const double lstop  = 2.0 * log(0.05);
    const double lstep  = 2.0 * log(0.9);
    for (int k = 0;; ++k) {
      const double v = lstart + k * lstep;
      if (!(v > lstop)) break;
      epsl[ne++] = (float)exp(v);
    }
  }
  epsl[ne++] = 0.0025f;

  (void)hipMemsetAsync(d_out, 0, sizeof(float), stream);

  // init at eps0
  sink_stream<0><<<1536, 256, 0, stream>>>(Gxy, Gxx, Gyy, potA, potA, colPart,
                                           epsl[0], nullptr);
  sink_merge<0><<<128, 256, 0, stream>>>(colPart, potA, potA, epsl[0], nullptr);

  // damped scan over the schedule
  float* cur = potA;
  float* nxt = potB;
  for (int i = 0; i < ne; ++i) {
    sink_stream<1><<<1536, 256, 0, stream>>>(Gxy, Gxx, Gyy, cur, nxt, colPart,
                                             epsl[i], nullptr);
    sink_merge<1><<<128, 256, 0, stream>>>(colPart, cur, nxt, epsl[i], nullptr);
    float* tmp = cur; cur = nxt; nxt = tmp;
  }

  // final extrapolation + loss
  sink_stream<2><<<1536, 256, 0, stream>>>(Gxy, Gxx, Gyy, cur, cur, colPart,
                                           epsl[ne - 1], out);
  sink_merge<2><<<128, 256, 0, stream>>>(colPart, cur, cur, epsl[ne - 1], out);
}